// Round 5
// baseline (2420.790 us; speedup 1.0000x reference)
//
#include <hip/hip_runtime.h>
#include <hip/hip_bf16.h>

#define CC 64
#define HH 512
#define WWI 512
#define HWX (HH*WWI)
#define CHWX (CC*HWX)
#define EPSV 1e-5f

using bf16 = __hip_bfloat16;

__device__ __forceinline__ float b2f(bf16 v){ return __bfloat162float(v); }
__device__ __forceinline__ bf16 f2b(float v){ return __float2bfloat16(v); }

// norm params from raw sums (block-uniform scalar math)
__device__ __forceinline__ void mk_norm(const float* s1, const float* s2, int c,
                                        float invN, float& m, float& r){
  m = s1[c] * invN;
  float v = fmaxf(s2[c] * invN - m * m, 0.f);
  r = rsqrtf(v + EPSV);
}

// 256-thread block. Reduce (v1,v2) across block, atomicAdd into s1,s2.
__device__ __forceinline__ void block_reduce_atomic(float v1, float v2,
                                                    float* s1, float* s2){
  #pragma unroll
  for (int o = 32; o > 0; o >>= 1){
    v1 += __shfl_down(v1, o);
    v2 += __shfl_down(v2, o);
  }
  __shared__ float a1[4], a2[4];
  int lane = threadIdx.x & 63, wid = threadIdx.x >> 6;
  if (lane == 0){ a1[wid] = v1; a2[wid] = v2; }
  __syncthreads();
  if (threadIdx.x == 0){
    atomicAdd(s1, a1[0]+a1[1]+a1[2]+a1[3]);
    atomicAdd(s2, a2[0]+a2[1]+a2[2]+a2[3]);
  }
}

// ======== fused morphology + depthwise conv + stats, one kernel ========
// CLOSING: maxpool2d then minpool2d (CLOS=true). OPENING: min then max.
// Then K x K depthwise conv (zero pad) on the morph result, 32x32 out tile.
template<int P, bool CLOS>
__global__ __launch_bounds__(256) void morphdw(const float* __restrict__ in,
    const float* __restrict__ wgt, const float* __restrict__ bias,
    float* __restrict__ outF, float* __restrict__ s1, float* __restrict__ s2){
  constexpr int K  = 2*P+1;
  constexpr int NI = 32+6*P;   // input tile
  constexpr int N1 = 32+4*P;   // pool-1 result region
  constexpr int N2 = 32+2*P;   // morph result region (dwconv input)
  __shared__ float b0[NI*(NI+1)];
  __shared__ float b1[NI*(N1+1)];
  const int c = blockIdx.z;
  const int x0 = blockIdx.x*32, y0 = blockIdx.y*32;
  const float* ip = in + (size_t)c*HWX;
  const int tid = threadIdx.x;
  // stage input, clamp-to-edge (exact for the first pool)
  for (int i = tid; i < NI*NI; i += 256){
    int r = i / NI, cc = i - r*NI;
    int gy = min(max(y0 - 3*P + r, 0), HH-1);
    int gx = min(max(x0 - 3*P + cc, 0), WWI-1);
    b0[r*(NI+1)+cc] = ip[gy*WWI+gx];
  }
  __syncthreads();
  // pass1: op1 horizontal
  for (int i = tid; i < NI*N1; i += 256){
    int r = i / N1, cc = i - r*N1;
    const float* p = &b0[r*(NI+1)+cc];
    float m = p[0];
    #pragma unroll
    for (int j = 1; j <= 2*P; ++j) m = CLOS ? fmaxf(m,p[j]) : fminf(m,p[j]);
    b1[r*(N1+1)+cc] = m;
  }
  __syncthreads();
  // pass2: op1 vertical; OOB positions -> op2-neutral (reduce_window pad)
  for (int i = tid; i < N1*N1; i += 256){
    int r = i / N1, cc = i - r*N1;
    const float* p = &b1[r*(N1+1)+cc];
    float m = p[0];
    #pragma unroll
    for (int j = 1; j <= 2*P; ++j)
      m = CLOS ? fmaxf(m,p[j*(N1+1)]) : fminf(m,p[j*(N1+1)]);
    int gy = y0-2*P+r, gx = x0-2*P+cc;
    bool ok = ((unsigned)gy < HH) && ((unsigned)gx < WWI);
    b0[r*(N1+1)+cc] = ok ? m : (CLOS ? 3.4e38f : -3.4e38f);
  }
  __syncthreads();
  // pass3: op2 horizontal
  for (int i = tid; i < N1*N2; i += 256){
    int r = i / N2, cc = i - r*N2;
    const float* p = &b0[r*(N1+1)+cc];
    float m = p[0];
    #pragma unroll
    for (int j = 1; j <= 2*P; ++j) m = CLOS ? fminf(m,p[j]) : fmaxf(m,p[j]);
    b1[r*(N2+1)+cc] = m;
  }
  __syncthreads();
  // pass4: op2 vertical; OOB -> 0 (dwconv zero pad)
  for (int i = tid; i < N2*N2; i += 256){
    int r = i / N2, cc = i - r*N2;
    const float* p = &b1[r*(N2+1)+cc];
    float m = p[0];
    #pragma unroll
    for (int j = 1; j <= 2*P; ++j)
      m = CLOS ? fminf(m,p[j*(N2+1)]) : fmaxf(m,p[j*(N2+1)]);
    int gy = y0-P+r, gx = x0-P+cc;
    bool ok = ((unsigned)gy < HH) && ((unsigned)gx < WWI);
    b0[r*(N2+1)+cc] = ok ? m : 0.f;
  }
  __syncthreads();
  // dwconv KxK on b0 (stride N2+1), 4 output rows per thread
  const float* wp = wgt + c*K*K;
  const int tx = tid & 31, tr0 = (tid >> 5)*4;
  float b = bias[c];
  float acc[4] = {b,b,b,b};
  #pragma unroll
  for (int dx = 0; dx < K; ++dx){
    float v[2*P+4];
    #pragma unroll
    for (int i2 = 0; i2 < 2*P+4; ++i2) v[i2] = b0[(tr0+i2)*(N2+1) + tx + dx];
    #pragma unroll
    for (int dy = 0; dy < K; ++dy){
      float w = wp[dy*K+dx];
      #pragma unroll
      for (int r = 0; r < 4; ++r) acc[r] += w*v[r+dy];
    }
  }
  float sv = 0.f, sq = 0.f;
  float* op = outF + (size_t)c*HWX;
  #pragma unroll
  for (int r = 0; r < 4; ++r){
    op[(y0+tr0+r)*WWI + x0+tx] = acc[r];
    sv += acc[r]; sq += acc[r]*acc[r];
  }
  block_reduce_atomic(sv, sq, s1+c, s2+c);
}

// -------- stats of d = sgn*(relu(norm(A)) - x); read-only, no d write ------
__global__ __launch_bounds__(256) void diff_stats4(const float4* __restrict__ A,
    const float4* __restrict__ x,
    const float* __restrict__ s1i, const float* __restrict__ s2i, float invN,
    float sgn, float* __restrict__ s1, float* __restrict__ s2){
  int c = blockIdx.z;
  float m, r;
  mk_norm(s1i, s2i, c, invN, m, r);
  size_t i = (size_t)c * (HWX/4) + blockIdx.x * 256 + threadIdx.x;
  float4 f = A[i], xv = x[i];
  float d0 = sgn * (fmaxf((f.x - m) * r, 0.f) - xv.x);
  float d1 = sgn * (fmaxf((f.y - m) * r, 0.f) - xv.y);
  float d2 = sgn * (fmaxf((f.z - m) * r, 0.f) - xv.z);
  float d3 = sgn * (fmaxf((f.w - m) * r, 0.f) - xv.w);
  block_reduce_atomic(d0+d1+d2+d3, d0*d0+d1*d1+d2*d2+d3*d3, s1 + c, s2 + c);
}

// ======== 3x3 dwconv of norm(d); d recomputed from A,x at stage time ======
__global__ __launch_bounds__(256) void conv3_acc(const float* __restrict__ A,
    const float* __restrict__ x,
    const float* __restrict__ s1A, const float* __restrict__ s2A,
    const float* __restrict__ s1D, const float* __restrict__ s2D, float invN,
    float sgn, const float* __restrict__ w3, const float* __restrict__ b3,
    float* __restrict__ comb, int first){
  __shared__ float S[34*35];
  const int c = blockIdx.z;
  const int x0 = blockIdx.x*32, y0 = blockIdx.y*32;
  float mA, rA, mD, rD;
  mk_norm(s1A, s2A, c, invN, mA, rA);
  mk_norm(s1D, s2D, c, invN, mD, rD);
  const float* ap = A + (size_t)c*HWX;
  const float* xp = x + (size_t)c*HWX;
  for (int i = threadIdx.x; i < 34*34; i += 256){
    int rr = i / 34, cc = i - rr*34;
    int gy = y0 - 1 + rr, gx = x0 - 1 + cc;
    bool ok = ((unsigned)gy < HH) && ((unsigned)gx < WWI);
    int ad = min(max(gy,0),HH-1)*WWI + min(max(gx,0),WWI-1);
    float dval = sgn * (fmaxf((ap[ad] - mA) * rA, 0.f) - xp[ad]);
    S[rr*35+cc] = ok ? (dval - mD) * rD : 0.f;
  }
  __syncthreads();
  const int tx = threadIdx.x & 31, tr0 = (threadIdx.x >> 5) * 4;
  float b = b3[c];
  const float* wp = w3 + c*9;
  float acc[4] = {b,b,b,b};
  #pragma unroll
  for (int dx = 0; dx < 3; ++dx){
    float v[6];
    #pragma unroll
    for (int i = 0; i < 6; ++i) v[i] = S[(tr0+i)*35 + tx + dx];
    #pragma unroll
    for (int dy = 0; dy < 3; ++dy){
      float w = wp[dy*3+dx];
      #pragma unroll
      for (int rr = 0; rr < 4; ++rr) acc[rr] += w * v[rr+dy];
    }
  }
  float* op = comb + (size_t)c*HWX;
  #pragma unroll
  for (int rr = 0; rr < 4; ++rr){
    size_t oi = (size_t)(y0+tr0+rr)*WWI + x0+tx;
    op[oi] = first ? acc[rr] : (op[oi] + acc[rr]);
  }
}

// ======== Conv3d #1: 4 d-planes per block, 6 staged comb planes ========
__global__ __launch_bounds__(256) void conv3d1(const float* __restrict__ comb,
    const float* __restrict__ wt, const float* __restrict__ bt,
    bf16* __restrict__ T, float* __restrict__ s1, float* __restrict__ s2){
  __shared__ float S[6][34*35];
  __shared__ float red[4][6];
  const int d0 = blockIdx.z * 4;
  const int x0 = blockIdx.x*32, y0 = blockIdx.y*32;
  #pragma unroll
  for (int j = 0; j < 6; ++j){
    int dz = d0 - 1 + j;
    bool zok = (unsigned)dz < CC;
    const float* ip = comb + (size_t)min(max(dz,0),CC-1) * HWX;
    for (int i = threadIdx.x; i < 34*34; i += 256){
      int rr = i / 34, cc = i - rr*34;
      int gy = y0 - 1 + rr, gx = x0 - 1 + cc;
      bool ok = zok && ((unsigned)gy < HH) && ((unsigned)gx < WWI);
      float v = ip[min(max(gy,0),HH-1)*WWI + min(max(gx,0),WWI-1)];
      S[j][rr*35+cc] = ok ? v : 0.f;
    }
  }
  __syncthreads();
  const int tx = threadIdx.x & 31, tr0 = (threadIdx.x >> 5) * 4;
  const int lane = threadIdx.x & 63, wid = threadIdx.x >> 6;
  for (int dl = 0; dl < 4; ++dl){
    const int d = d0 + dl;
    float acc[3][4];
    #pragma unroll
    for (int oc = 0; oc < 3; ++oc){
      float b = bt[oc];
      #pragma unroll
      for (int rr = 0; rr < 4; ++rr) acc[oc][rr] = b;
    }
    #pragma unroll
    for (int dd = 0; dd < 3; ++dd){
      #pragma unroll
      for (int dx = 0; dx < 3; ++dx){
        float v[6];
        #pragma unroll
        for (int i = 0; i < 6; ++i) v[i] = S[dl+dd][(tr0+i)*35 + tx + dx];
        #pragma unroll
        for (int dy = 0; dy < 3; ++dy){
          #pragma unroll
          for (int oc = 0; oc < 3; ++oc){
            float w = wt[oc*27 + dd*9 + dy*3 + dx];
            #pragma unroll
            for (int rr = 0; rr < 4; ++rr) acc[oc][rr] += w * v[rr+dy];
          }
        }
      }
    }
    float vals[6] = {0,0,0,0,0,0};
    #pragma unroll
    for (int oc = 0; oc < 3; ++oc){
      bf16* tp = T + (size_t)(oc*CC + d)*HWX;
      #pragma unroll
      for (int rr = 0; rr < 4; ++rr){
        bf16 h = f2b(acc[oc][rr]);
        tp[(size_t)(y0+tr0+rr)*WWI + x0+tx] = h;
        float av = b2f(h);                 // stats match stored bf16
        vals[2*oc]   += av;
        vals[2*oc+1] += av*av;
      }
    }
    #pragma unroll
    for (int o = 32; o > 0; o >>= 1)
      #pragma unroll
      for (int k = 0; k < 6; ++k) vals[k] += __shfl_down(vals[k], o);
    __syncthreads();                       // protect red[] from prev iter
    if (lane == 0)
      #pragma unroll
      for (int k = 0; k < 6; ++k) red[wid][k] = vals[k];
    __syncthreads();
    if (threadIdx.x == 0){
      #pragma unroll
      for (int oc = 0; oc < 3; ++oc){
        atomicAdd(s1 + oc*CC + d, red[0][2*oc]  +red[1][2*oc]  +red[2][2*oc]  +red[3][2*oc]);
        atomicAdd(s2 + oc*CC + d, red[0][2*oc+1]+red[1][2*oc+1]+red[2][2*oc+1]+red[3][2*oc+1]);
      }
    }
  }
}

// ======== Conv3d #2: 4 d per block, 18 relu-norm planes staged bf16 ======
__global__ __launch_bounds__(256) void conv3d2_final(const bf16* __restrict__ T,
    const float* __restrict__ s1i, const float* __restrict__ s2i, float invN,
    const float* __restrict__ wt2, const float* __restrict__ bt2,
    const float* __restrict__ x, float* __restrict__ out){
  __shared__ bf16 S16[18][34*36];          // 44 KB
  const int d0 = blockIdx.z * 4;
  const int x0 = blockIdx.x*32, y0 = blockIdx.y*32;
  #pragma unroll
  for (int j = 0; j < 6; ++j){
    int dz = d0 - 1 + j;
    bool zok = (unsigned)dz < CC;
    int dzc = min(max(dz,0),CC-1);
    #pragma unroll
    for (int i3 = 0; i3 < 3; ++i3){
      int ch = i3*CC + dzc;
      float m, r;
      mk_norm(s1i, s2i, ch, invN, m, r);
      const bf16* tp = T + (size_t)ch * HWX;
      bf16* sp = S16[i3*6 + j];
      for (int i = threadIdx.x; i < 34*34; i += 256){
        int rr = i / 34, cc = i - rr*34;
        int gy = y0 - 1 + rr, gx = x0 - 1 + cc;
        bool ok = zok && ((unsigned)gy < HH) && ((unsigned)gx < WWI);
        float tv = b2f(tp[min(max(gy,0),HH-1)*WWI + min(max(gx,0),WWI-1)]);
        float u = ok ? fmaxf((tv - m) * r, 0.f) : 0.f;
        sp[rr*36+cc] = f2b(u);
      }
    }
  }
  __syncthreads();
  const int tx = threadIdx.x & 31, tr0 = (threadIdx.x >> 5) * 4;
  for (int dl = 0; dl < 4; ++dl){
    const int d = d0 + dl;
    float b = bt2[0];
    float acc[4] = {b,b,b,b};
    #pragma unroll
    for (int i3 = 0; i3 < 3; ++i3){
      #pragma unroll
      for (int dd = 0; dd < 3; ++dd){
        const bf16* sp = S16[i3*6 + dl + dd];
        #pragma unroll
        for (int dx = 0; dx < 3; ++dx){
          float v[6];
          #pragma unroll
          for (int i = 0; i < 6; ++i) v[i] = b2f(sp[(tr0+i)*36 + tx + dx]);
          #pragma unroll
          for (int dy = 0; dy < 3; ++dy){
            float w = wt2[(i3*3+dd)*9 + dy*3 + dx];
            #pragma unroll
            for (int rr = 0; rr < 4; ++rr) acc[rr] += w * v[rr+dy];
          }
        }
      }
    }
    #pragma unroll
    for (int rr = 0; rr < 4; ++rr){
      float sg = 1.f / (1.f + __expf(-acc[rr]));
      size_t gi = (size_t)d*HWX + (size_t)(y0+tr0+rr)*WWI + x0+tx;
      out[gi] = fmaxf(x[gi] * sg, 0.f);
    }
  }
}

extern "C" void kernel_launch(void* const* d_in, const int* in_sizes, int n_in,
                              void* d_out, int out_size, void* d_ws, size_t ws_size,
                              hipStream_t stream){
  const float* x     = (const float*)d_in[0];
  const float* w_wt5 = (const float*)d_in[1];
  const float* b_wt5 = (const float*)d_in[2];
  const float* w_wt9 = (const float*)d_in[3];
  const float* b_wt9 = (const float*)d_in[4];
  const float* w_bt5 = (const float*)d_in[5];
  const float* b_bt5 = (const float*)d_in[6];
  const float* w_bt9 = (const float*)d_in[7];
  const float* b_bt9 = (const float*)d_in[8];
  const float* w_wn  = (const float*)d_in[9];
  const float* b_wn  = (const float*)d_in[10];
  const float* w_t1  = (const float*)d_in[11];
  const float* b_t1  = (const float*)d_in[12];
  const float* w_t2  = (const float*)d_in[13];
  const float* b_t2  = (const float*)d_in[14];
  float* out = (float*)d_out;

  // ---- workspace layout (same 201 MB footprint as round 4) ----
  char* ws = (char*)d_ws;
  float* A    = (float*)ws;                  // dwconv out (per branch)
  float* comb = (float*)(ws + 2*(size_t)CHWX*4);  // accumulator
  bf16*  T    = (bf16*)ws;                   // 3*CHWX bf16, overlays A + spare
  float* stats = comb + (size_t)CHWX;
  float* s1 = stats;        // 704
  float* s2 = stats + 704;  // 704

  hipMemsetAsync(s1, 0, 1408 * sizeof(float), stream);

  dim3 blk(256);
  dim3 gridM(WWI/32, HH/32, CC);            // (16,16,64)
  dim3 gridM4(WWI/32, HH/32, CC/4);         // (16,16,16)
  dim3 gridV(HWX/4/256, 1, CC);             // (256,1,64) float4 streaming
  float invHW = 1.f / (float)HWX;

  int first = 1;
  for (int ki = 0; ki < 2; ++ki){
    for (int br = 0; br < 2; ++br){
      int st = (ki * 2 + br) * 2;
      // ---- fused morphology + dwconv + stats -> A ----
      if (ki == 0){
        if (br == 0) morphdw<2, true ><<<gridM, blk, 0, stream>>>(x, w_wt5, b_wt5, A, s1+st*64, s2+st*64);
        else         morphdw<2, false><<<gridM, blk, 0, stream>>>(x, w_bt5, b_bt5, A, s1+st*64, s2+st*64);
      } else {
        if (br == 0) morphdw<4, true ><<<gridM, blk, 0, stream>>>(x, w_wt9, b_wt9, A, s1+st*64, s2+st*64);
        else         morphdw<4, false><<<gridM, blk, 0, stream>>>(x, w_bt9, b_bt9, A, s1+st*64, s2+st*64);
      }
      float sgn = (br == 0) ? -1.f : 1.f;   // WTHAM: x - wth ; BTHAM: bth - x
      diff_stats4<<<gridV, blk, 0, stream>>>((const float4*)A, (const float4*)x,
                                             s1 + st*64, s2 + st*64, invHW, sgn,
                                             s1 + (st+1)*64, s2 + (st+1)*64);
      conv3_acc<<<gridM, blk, 0, stream>>>(A, x, s1 + st*64, s2 + st*64,
                                           s1 + (st+1)*64, s2 + (st+1)*64, invHW,
                                           sgn, w_wn, b_wn, comb, first);
      first = 0;
    }
  }

  // ---- temporal cross ----
  conv3d1<<<gridM4, blk, 0, stream>>>(comb, w_t1, b_t1, T, s1 + 512, s2 + 512);
  conv3d2_final<<<gridM4, blk, 0, stream>>>(T, s1 + 512, s2 + 512, invHW,
                                            w_t2, b_t2, x, out);
}

// Round 6
// 1788.206 us; speedup vs baseline: 1.3538x; 1.3538x over previous
//
#include <hip/hip_runtime.h>
#include <hip/hip_bf16.h>

#define CC 64
#define HH 512
#define WWI 512
#define HWX (HH*WWI)
#define CHWX (CC*HWX)
#define EPSV 1e-5f

using bf16 = __hip_bfloat16;

__device__ __forceinline__ float b2f(bf16 v){ return __bfloat162float(v); }
__device__ __forceinline__ bf16 f2b(float v){ return __float2bfloat16(v); }
__device__ __forceinline__ float u2f(unsigned short u){
  unsigned int x = ((unsigned int)u) << 16;
  float f; __builtin_memcpy(&f, &x, 4); return f;
}

template<bool MX>
__device__ __forceinline__ float opf(float a, float b){
  return MX ? fmaxf(a,b) : fminf(a,b);
}
template<bool MX>
__device__ __forceinline__ float4 opf4(float4 a, float4 b){
  return make_float4(opf<MX>(a.x,b.x), opf<MX>(a.y,b.y),
                     opf<MX>(a.z,b.z), opf<MX>(a.w,b.w));
}

// norm params from raw sums (block-uniform scalar math)
__device__ __forceinline__ void mk_norm(const float* s1, const float* s2, int c,
                                        float invN, float& m, float& r){
  m = s1[c] * invN;
  float v = fmaxf(s2[c] * invN - m * m, 0.f);
  r = rsqrtf(v + EPSV);
}

// 256-thread block. Reduce (v1,v2) across block, atomicAdd into s1,s2.
__device__ __forceinline__ void block_reduce_atomic(float v1, float v2,
                                                    float* s1, float* s2){
  #pragma unroll
  for (int o = 32; o > 0; o >>= 1){
    v1 += __shfl_down(v1, o);
    v2 += __shfl_down(v2, o);
  }
  __shared__ float a1[4], a2[4];
  int lane = threadIdx.x & 63, wid = threadIdx.x >> 6;
  if (lane == 0){ a1[wid] = v1; a2[wid] = v2; }
  __syncthreads();
  if (threadIdx.x == 0){
    atomicAdd(s1, a1[0]+a1[1]+a1[2]+a1[3]);
    atomicAdd(s2, a2[0]+a2[1]+a2[2]+a2[3]);
  }
}

// ======== fused morphology + depthwise conv + stats, float4 LDS passes ====
// CLOSING: maxpool2d then minpool2d (CLOS=true). OPENING: min then max.
template<int P, bool CLOS>
__global__ __launch_bounds__(256) void morphdw(const float* __restrict__ in,
    const float* __restrict__ wgt, const float* __restrict__ bias,
    float* __restrict__ outF, float* __restrict__ s1, float* __restrict__ s2){
  constexpr int K  = 2*P+1;
  constexpr int NI = 32+6*P;   // input tile (div by 4)
  constexpr int N1 = 32+4*P;   // pool-1 region
  constexpr int N2 = 32+2*P;   // morph region (dwconv input)
  constexpr int C1 = N1/4, C2 = N2/4;
  __shared__ __align__(16) float b0[NI*NI];
  __shared__ __align__(16) float b1[NI*N1];
  const int c = blockIdx.z;
  const int x0 = blockIdx.x*32, y0 = blockIdx.y*32;
  const float* ip = in + (size_t)c*HWX;
  const int tid = threadIdx.x;
  // stage input, clamp-to-edge (exact for the first pool)
  for (int i = tid; i < NI*NI; i += 256){
    int r = i / NI, cc = i - r*NI;
    int gy = min(max(y0 - 3*P + r, 0), HH-1);
    int gx = min(max(x0 - 3*P + cc, 0), WWI-1);
    b0[i] = ip[gy*WWI+gx];
  }
  __syncthreads();
  // pass1: op1 horizontal, b0(NI x NI) -> b1(NI x N1)
  for (int i = tid; i < NI*C1; i += 256){
    int r = i / C1, cg = i - r*C1;
    const float* p = &b0[r*NI + 4*cg];
    float v[4+2*P];
    #pragma unroll
    for (int q = 0; q < (4+2*P)/4; ++q){
      float4 t = *(const float4*)(p + 4*q);
      v[4*q]=t.x; v[4*q+1]=t.y; v[4*q+2]=t.z; v[4*q+3]=t.w;
    }
    float cm = v[3];
    #pragma unroll
    for (int q = 4; q <= 2*P; ++q) cm = opf<CLOS>(cm, v[q]);
    float4 o;
    o.x = opf<CLOS>(opf<CLOS>(opf<CLOS>(cm, v[0]), v[1]), v[2]);
    o.y = opf<CLOS>(opf<CLOS>(opf<CLOS>(cm, v[1]), v[2]), v[2*P+1]);
    o.z = opf<CLOS>(opf<CLOS>(opf<CLOS>(cm, v[2]), v[2*P+1]), v[2*P+2]);
    o.w = opf<CLOS>(opf<CLOS>(opf<CLOS>(cm, v[2*P+1]), v[2*P+2]), v[2*P+3]);
    *(float4*)&b1[r*N1 + 4*cg] = o;
  }
  __syncthreads();
  // pass2: op1 vertical + OOB -> op2-neutral; b1 -> b0(N1 x N1)
  for (int i = tid; i < N1*C1; i += 256){
    int r = i / C1, cg = i - r*C1;
    float4 m = *(const float4*)&b1[r*N1 + 4*cg];
    #pragma unroll
    for (int q = 1; q <= 2*P; ++q)
      m = opf4<CLOS>(m, *(const float4*)&b1[(r+q)*N1 + 4*cg]);
    int gy = y0 - 2*P + r;
    bool oky = (unsigned)gy < HH;
    int gx = x0 - 2*P + 4*cg;
    const float neut = CLOS ? 3.4e38f : -3.4e38f;
    m.x = (oky && (unsigned)(gx  ) < WWI) ? m.x : neut;
    m.y = (oky && (unsigned)(gx+1) < WWI) ? m.y : neut;
    m.z = (oky && (unsigned)(gx+2) < WWI) ? m.z : neut;
    m.w = (oky && (unsigned)(gx+3) < WWI) ? m.w : neut;
    *(float4*)&b0[r*N1 + 4*cg] = m;
  }
  __syncthreads();
  // pass3: op2 horizontal, b0(N1 x N1) -> b1(N1 x N2)
  for (int i = tid; i < N1*C2; i += 256){
    int r = i / C2, cg = i - r*C2;
    const float* p = &b0[r*N1 + 4*cg];
    float v[4+2*P];
    #pragma unroll
    for (int q = 0; q < (4+2*P)/4; ++q){
      float4 t = *(const float4*)(p + 4*q);
      v[4*q]=t.x; v[4*q+1]=t.y; v[4*q+2]=t.z; v[4*q+3]=t.w;
    }
    float cm = v[3];
    #pragma unroll
    for (int q = 4; q <= 2*P; ++q) cm = opf<!CLOS>(cm, v[q]);
    float4 o;
    o.x = opf<!CLOS>(opf<!CLOS>(opf<!CLOS>(cm, v[0]), v[1]), v[2]);
    o.y = opf<!CLOS>(opf<!CLOS>(opf<!CLOS>(cm, v[1]), v[2]), v[2*P+1]);
    o.z = opf<!CLOS>(opf<!CLOS>(opf<!CLOS>(cm, v[2]), v[2*P+1]), v[2*P+2]);
    o.w = opf<!CLOS>(opf<!CLOS>(opf<!CLOS>(cm, v[2*P+1]), v[2*P+2]), v[2*P+3]);
    *(float4*)&b1[r*N2 + 4*cg] = o;
  }
  __syncthreads();
  // pass4: op2 vertical + OOB -> 0 (dwconv zero pad); b1 -> b0(N2 x N2)
  for (int i = tid; i < N2*C2; i += 256){
    int r = i / C2, cg = i - r*C2;
    float4 m = *(const float4*)&b1[r*N2 + 4*cg];
    #pragma unroll
    for (int q = 1; q <= 2*P; ++q)
      m = opf4<!CLOS>(m, *(const float4*)&b1[(r+q)*N2 + 4*cg]);
    int gy = y0 - P + r;
    bool oky = (unsigned)gy < HH;
    int gx = x0 - P + 4*cg;
    m.x = (oky && (unsigned)(gx  ) < WWI) ? m.x : 0.f;
    m.y = (oky && (unsigned)(gx+1) < WWI) ? m.y : 0.f;
    m.z = (oky && (unsigned)(gx+2) < WWI) ? m.z : 0.f;
    m.w = (oky && (unsigned)(gx+3) < WWI) ? m.w : 0.f;
    *(float4*)&b0[r*N2 + 4*cg] = m;
  }
  __syncthreads();
  // pass5: dwconv KxK, thread = 1 row x 4 cols
  const float* wp = wgt + c*K*K;
  const int cg = tid & 7, row = tid >> 3;
  const int c0 = 4*cg;
  float bb = bias[c];
  float a0=bb, a1=bb, a2=bb, a3=bb;
  #pragma unroll
  for (int dy = 0; dy < K; ++dy){
    float v[4+2*P];
    const float* p = &b0[(row+dy)*N2 + c0];
    #pragma unroll
    for (int q = 0; q < (4+2*P)/4; ++q){
      float4 t = *(const float4*)(p + 4*q);
      v[4*q]=t.x; v[4*q+1]=t.y; v[4*q+2]=t.z; v[4*q+3]=t.w;
    }
    #pragma unroll
    for (int dx = 0; dx < K; ++dx){
      float w = wp[dy*K+dx];
      a0 += w*v[dx]; a1 += w*v[dx+1]; a2 += w*v[dx+2]; a3 += w*v[dx+3];
    }
  }
  float* op = outF + (size_t)c*HWX;
  *(float4*)&op[(y0+row)*WWI + x0 + c0] = make_float4(a0,a1,a2,a3);
  block_reduce_atomic(a0+a1+a2+a3, a0*a0+a1*a1+a2*a2+a3*a3, s1+c, s2+c);
}

// -------- stats of d = sgn*(relu(norm(A)) - x); grid-stride x4 ----------
__global__ __launch_bounds__(256) void diff_stats4(const float4* __restrict__ A,
    const float4* __restrict__ x,
    const float* __restrict__ s1i, const float* __restrict__ s2i, float invN,
    float sgn, float* __restrict__ s1, float* __restrict__ s2){
  int c = blockIdx.z;
  float m, r;
  mk_norm(s1i, s2i, c, invN, m, r);
  size_t base = (size_t)c * (HWX/4) + blockIdx.x * 1024 + threadIdx.x;
  float sv = 0.f, sq = 0.f;
  #pragma unroll
  for (int k = 0; k < 4; ++k){
    size_t i = base + k*256;
    float4 f = A[i], xv = x[i];
    float d0 = sgn * (fmaxf((f.x - m) * r, 0.f) - xv.x);
    float d1 = sgn * (fmaxf((f.y - m) * r, 0.f) - xv.y);
    float d2 = sgn * (fmaxf((f.z - m) * r, 0.f) - xv.z);
    float d3 = sgn * (fmaxf((f.w - m) * r, 0.f) - xv.w);
    sv += d0+d1+d2+d3;
    sq += d0*d0+d1*d1+d2*d2+d3*d3;
  }
  block_reduce_atomic(sv, sq, s1 + c, s2 + c);
}

// ======== 3x3 dwconv of norm(d); d recomputed from A,x; row x 4col =======
__global__ __launch_bounds__(256) void conv3_acc(const float* __restrict__ A,
    const float* __restrict__ x,
    const float* __restrict__ s1A, const float* __restrict__ s2A,
    const float* __restrict__ s1D, const float* __restrict__ s2D, float invN,
    float sgn, const float* __restrict__ w3, const float* __restrict__ b3,
    float* __restrict__ comb, int first){
  __shared__ __align__(16) float S[34*36];
  const int c = blockIdx.z;
  const int x0 = blockIdx.x*32, y0 = blockIdx.y*32;
  float mA, rA, mD, rD;
  mk_norm(s1A, s2A, c, invN, mA, rA);
  mk_norm(s1D, s2D, c, invN, mD, rD);
  const float* ap = A + (size_t)c*HWX;
  const float* xp = x + (size_t)c*HWX;
  for (int i = threadIdx.x; i < 34*34; i += 256){
    int rr = i / 34, cc = i - rr*34;
    int gy = y0 - 1 + rr, gx = x0 - 1 + cc;
    bool ok = ((unsigned)gy < HH) && ((unsigned)gx < WWI);
    int ad = min(max(gy,0),HH-1)*WWI + min(max(gx,0),WWI-1);
    float dval = sgn * (fmaxf((ap[ad] - mA) * rA, 0.f) - xp[ad]);
    S[rr*36+cc] = ok ? (dval - mD) * rD : 0.f;
  }
  __syncthreads();
  const int cg = threadIdx.x & 7, row = threadIdx.x >> 3;
  const int c0 = 4*cg;
  const float* wp = w3 + c*9;
  float bb = b3[c];
  float acc[4] = {bb,bb,bb,bb};
  #pragma unroll
  for (int dy = 0; dy < 3; ++dy){
    const float* p = &S[(row+dy)*36 + c0];
    float4 t0 = *(const float4*)p;
    float4 t1 = *(const float4*)(p+4);
    float v[6] = {t0.x,t0.y,t0.z,t0.w,t1.x,t1.y};
    #pragma unroll
    for (int dx = 0; dx < 3; ++dx){
      float w = wp[dy*3+dx];
      #pragma unroll
      for (int j = 0; j < 4; ++j) acc[j] += w * v[j+dx];
    }
  }
  float4* cp = (float4*)&comb[(size_t)c*HWX + (y0+row)*WWI + x0 + c0];
  float4 o = make_float4(acc[0],acc[1],acc[2],acc[3]);
  if (!first){
    float4 prev = *cp;
    o.x += prev.x; o.y += prev.y; o.z += prev.z; o.w += prev.w;
  }
  *cp = o;
}

// ======== Conv3d #1: 4 d-planes per block, 6 staged planes, row x 4col ====
__global__ __launch_bounds__(256) void conv3d1(const float* __restrict__ comb,
    const float* __restrict__ wt, const float* __restrict__ bt,
    bf16* __restrict__ T, float* __restrict__ s1, float* __restrict__ s2){
  __shared__ __align__(16) float S[6][34*36];
  __shared__ float red[4][6];
  const int d0 = blockIdx.z * 4;
  const int x0 = blockIdx.x*32, y0 = blockIdx.y*32;
  #pragma unroll
  for (int j = 0; j < 6; ++j){
    int dz = d0 - 1 + j;
    bool zok = (unsigned)dz < CC;
    const float* ip = comb + (size_t)min(max(dz,0),CC-1) * HWX;
    for (int i = threadIdx.x; i < 34*34; i += 256){
      int rr = i / 34, cc = i - rr*34;
      int gy = y0 - 1 + rr, gx = x0 - 1 + cc;
      bool ok = zok && ((unsigned)gy < HH) && ((unsigned)gx < WWI);
      float v = ip[min(max(gy,0),HH-1)*WWI + min(max(gx,0),WWI-1)];
      S[j][rr*36+cc] = ok ? v : 0.f;
    }
  }
  __syncthreads();
  const int cg = threadIdx.x & 7, row = threadIdx.x >> 3;
  const int c0 = 4*cg;
  const int lane = threadIdx.x & 63, wid = threadIdx.x >> 6;
  for (int dl = 0; dl < 4; ++dl){
    const int d = d0 + dl;
    float acc[3][4];
    #pragma unroll
    for (int oc = 0; oc < 3; ++oc){
      float b = bt[oc];
      #pragma unroll
      for (int j = 0; j < 4; ++j) acc[oc][j] = b;
    }
    #pragma unroll
    for (int dd = 0; dd < 3; ++dd){
      const float* sp = S[dl+dd];
      #pragma unroll
      for (int dy = 0; dy < 3; ++dy){
        const float* p = &sp[(row+dy)*36 + c0];
        float4 t0 = *(const float4*)p;
        float4 t1 = *(const float4*)(p+4);
        float v[6] = {t0.x,t0.y,t0.z,t0.w,t1.x,t1.y};
        #pragma unroll
        for (int dx = 0; dx < 3; ++dx){
          #pragma unroll
          for (int oc = 0; oc < 3; ++oc){
            float w = wt[oc*27 + dd*9 + dy*3 + dx];
            #pragma unroll
            for (int j = 0; j < 4; ++j) acc[oc][j] += w * v[j+dx];
          }
        }
      }
    }
    float vals[6] = {0,0,0,0,0,0};
    #pragma unroll
    for (int oc = 0; oc < 3; ++oc){
      bf16* tp = T + (size_t)(oc*CC + d)*HWX;
      union { ushort4 u; bf16 h[4]; } pk;
      #pragma unroll
      for (int j = 0; j < 4; ++j){
        pk.h[j] = f2b(acc[oc][j]);
        float av = b2f(pk.h[j]);          // stats match stored bf16
        vals[2*oc]   += av;
        vals[2*oc+1] += av*av;
      }
      *(ushort4*)&tp[(size_t)(y0+row)*WWI + x0 + c0] = pk.u;
    }
    #pragma unroll
    for (int o = 32; o > 0; o >>= 1)
      #pragma unroll
      for (int k = 0; k < 6; ++k) vals[k] += __shfl_down(vals[k], o);
    __syncthreads();                      // protect red[] from prev iter
    if (lane == 0)
      #pragma unroll
      for (int k = 0; k < 6; ++k) red[wid][k] = vals[k];
    __syncthreads();
    if (threadIdx.x == 0){
      #pragma unroll
      for (int oc = 0; oc < 3; ++oc){
        atomicAdd(s1 + oc*CC + d, red[0][2*oc]  +red[1][2*oc]  +red[2][2*oc]  +red[3][2*oc]);
        atomicAdd(s2 + oc*CC + d, red[0][2*oc+1]+red[1][2*oc+1]+red[2][2*oc+1]+red[3][2*oc+1]);
      }
    }
  }
}

// ======== Conv3d #2: 18 relu-norm bf16 planes (pitch 40), row x 4col =====
__global__ __launch_bounds__(256) void conv3d2_final(const bf16* __restrict__ T,
    const float* __restrict__ s1i, const float* __restrict__ s2i, float invN,
    const float* __restrict__ wt2, const float* __restrict__ bt2,
    const float* __restrict__ x, float* __restrict__ out){
  __shared__ __align__(16) bf16 S16[18][34*40];   // 48960 B
  const int d0 = blockIdx.z * 4;
  const int x0 = blockIdx.x*32, y0 = blockIdx.y*32;
  #pragma unroll
  for (int j = 0; j < 6; ++j){
    int dz = d0 - 1 + j;
    bool zok = (unsigned)dz < CC;
    int dzc = min(max(dz,0),CC-1);
    #pragma unroll
    for (int i3 = 0; i3 < 3; ++i3){
      int ch = i3*CC + dzc;
      float m, r;
      mk_norm(s1i, s2i, ch, invN, m, r);
      const bf16* tp = T + (size_t)ch * HWX;
      bf16* sp = S16[i3*6 + j];
      for (int i = threadIdx.x; i < 34*34; i += 256){
        int rr = i / 34, cc = i - rr*34;
        int gy = y0 - 1 + rr, gx = x0 - 1 + cc;
        bool ok = zok && ((unsigned)gy < HH) && ((unsigned)gx < WWI);
        float tv = b2f(tp[min(max(gy,0),HH-1)*WWI + min(max(gx,0),WWI-1)]);
        float u = ok ? fmaxf((tv - m) * r, 0.f) : 0.f;
        sp[rr*40+cc] = f2b(u);
      }
    }
  }
  __syncthreads();
  const int cg = threadIdx.x & 7, row = threadIdx.x >> 3;
  const int c0 = 4*cg;
  for (int dl = 0; dl < 4; ++dl){
    const int d = d0 + dl;
    float bb = bt2[0];
    float acc[4] = {bb,bb,bb,bb};
    #pragma unroll
    for (int i3 = 0; i3 < 3; ++i3){
      #pragma unroll
      for (int dd = 0; dd < 3; ++dd){
        const bf16* sp = S16[i3*6 + dl + dd];
        #pragma unroll
        for (int dy = 0; dy < 3; ++dy){
          const bf16* p = &sp[(row+dy)*40 + c0];
          ushort4 lo = *(const ushort4*)p;
          ushort2 hi = *(const ushort2*)(p+4);
          float v[6] = {u2f(lo.x),u2f(lo.y),u2f(lo.z),u2f(lo.w),
                        u2f(hi.x),u2f(hi.y)};
          #pragma unroll
          for (int dx = 0; dx < 3; ++dx){
            float w = wt2[(i3*3+dd)*9 + dy*3 + dx];
            #pragma unroll
            for (int j = 0; j < 4; ++j) acc[j] += w * v[j+dx];
          }
        }
      }
    }
    size_t gi = (size_t)d*HWX + (size_t)(y0+row)*WWI + x0 + c0;
    float4 xv = *(const float4*)&x[gi];
    float4 o;
    o.x = fmaxf(xv.x / (1.f + __expf(-acc[0])), 0.f);
    o.y = fmaxf(xv.y / (1.f + __expf(-acc[1])), 0.f);
    o.z = fmaxf(xv.z / (1.f + __expf(-acc[2])), 0.f);
    o.w = fmaxf(xv.w / (1.f + __expf(-acc[3])), 0.f);
    *(float4*)&out[gi] = o;
  }
}

extern "C" void kernel_launch(void* const* d_in, const int* in_sizes, int n_in,
                              void* d_out, int out_size, void* d_ws, size_t ws_size,
                              hipStream_t stream){
  const float* x     = (const float*)d_in[0];
  const float* w_wt5 = (const float*)d_in[1];
  const float* b_wt5 = (const float*)d_in[2];
  const float* w_wt9 = (const float*)d_in[3];
  const float* b_wt9 = (const float*)d_in[4];
  const float* w_bt5 = (const float*)d_in[5];
  const float* b_bt5 = (const float*)d_in[6];
  const float* w_bt9 = (const float*)d_in[7];
  const float* b_bt9 = (const float*)d_in[8];
  const float* w_wn  = (const float*)d_in[9];
  const float* b_wn  = (const float*)d_in[10];
  const float* w_t1  = (const float*)d_in[11];
  const float* b_t1  = (const float*)d_in[12];
  const float* w_t2  = (const float*)d_in[13];
  const float* b_t2  = (const float*)d_in[14];
  float* out = (float*)d_out;

  // ---- workspace layout (same as round 5) ----
  char* ws = (char*)d_ws;
  float* A    = (float*)ws;                        // branch dwconv out
  float* comb = (float*)(ws + 2*(size_t)CHWX*4);   // accumulator
  bf16*  T    = (bf16*)ws;                         // 3*CHWX bf16 overlay
  float* stats = comb + (size_t)CHWX;
  float* s1 = stats;        // 704
  float* s2 = stats + 704;  // 704

  hipMemsetAsync(s1, 0, 1408 * sizeof(float), stream);

  dim3 blk(256);
  dim3 gridM(WWI/32, HH/32, CC);            // (16,16,64)
  dim3 gridM4(WWI/32, HH/32, CC/4);         // (16,16,16)
  dim3 gridD(64, 1, CC);                    // diff grid-stride x4
  float invHW = 1.f / (float)HWX;

  int first = 1;
  for (int ki = 0; ki < 2; ++ki){
    for (int br = 0; br < 2; ++br){
      int st = (ki * 2 + br) * 2;
      if (ki == 0){
        if (br == 0) morphdw<2, true ><<<gridM, blk, 0, stream>>>(x, w_wt5, b_wt5, A, s1+st*64, s2+st*64);
        else         morphdw<2, false><<<gridM, blk, 0, stream>>>(x, w_bt5, b_bt5, A, s1+st*64, s2+st*64);
      } else {
        if (br == 0) morphdw<4, true ><<<gridM, blk, 0, stream>>>(x, w_wt9, b_wt9, A, s1+st*64, s2+st*64);
        else         morphdw<4, false><<<gridM, blk, 0, stream>>>(x, w_bt9, b_bt9, A, s1+st*64, s2+st*64);
      }
      float sgn = (br == 0) ? -1.f : 1.f;   // WTHAM: x - wth ; BTHAM: bth - x
      diff_stats4<<<gridD, blk, 0, stream>>>((const float4*)A, (const float4*)x,
                                             s1 + st*64, s2 + st*64, invHW, sgn,
                                             s1 + (st+1)*64, s2 + (st+1)*64);
      conv3_acc<<<gridM, blk, 0, stream>>>(A, x, s1 + st*64, s2 + st*64,
                                           s1 + (st+1)*64, s2 + (st+1)*64, invHW,
                                           sgn, w_wn, b_wn, comb, first);
      first = 0;
    }
  }

  // ---- temporal cross ----
  conv3d1<<<gridM4, blk, 0, stream>>>(comb, w_t1, b_t1, T, s1 + 512, s2 + 512);
  conv3d2_final<<<gridM4, blk, 0, stream>>>(T, s1 + 512, s2 + 512, invHW,
                                            w_t2, b_t2, x, out);
}